// Round 8
// baseline (178.103 us; speedup 1.0000x reference)
//
#include <hip/hip_runtime.h>
#include <hip/hip_bf16.h>
#include <stdint.h>

#define N_NODES 50000
#define N_EDGES 800000
#define D 128
#define NLAYER 3
#define NGROUP (N_NODES / 16)     // 3125 groups of 16 nodes
#define CAPG 384                   // max edges per group (Poisson(256) + 8 sigma)
#define GSTRIDE 512                // segment stride (slack for prefetch reads)
#define MAXCH 12                   // CAPG/32
#define EPB 1024
#define SC_BLOCKS ((N_EDGES + EPB - 1) / EPB)  // 782

typedef __attribute__((ext_vector_type(8))) short bf16x8;
typedef __attribute__((ext_vector_type(4))) float f32x4;

__device__ __forceinline__ short f2bf(float f) {
    union { float f; uint32_t u; } v; v.f = f;
    uint32_t u = v.u;
    uint32_t r = u + 0x7fffu + ((u >> 16) & 1u);   // round-to-nearest-even
    return (short)(r >> 16);
}
__device__ __forceinline__ float bf2f(short s) {
    union { uint32_t u; float f; } v;
    v.u = ((uint32_t)(uint16_t)s) << 16;
    return v.f;
}

// ---------------------------------------------------------------------------
// Weight conversion: bf16, B-fragment-swizzled (one 16B load per lane-frag).
// ---------------------------------------------------------------------------
__global__ void wconv(const float* __restrict__ W1, const float* __restrict__ W2,
                      short* __restrict__ Wswz) {
    int t = blockIdx.x * blockDim.x + threadIdx.x;   // (l,mat,ks,nt,lane)
    if (t >= NLAYER * 2 * 4 * 8 * 64) return;
    int lane = t & 63;
    int nt   = (t >> 6) & 7;
    int ks   = (t >> 9) & 3;
    int mat  = (t >> 11) & 1;
    int l    = t >> 12;
    const float* W = (mat == 0 ? W1 : W2) + (size_t)l * D * D;
    int n = nt * 16 + (lane & 15);
    short* outp = Wswz + (size_t)t * 8;
#pragma unroll
    for (int j = 0; j < 8; ++j) {
        int k = ks * 32 + (lane >> 4) * 8 + j;
        outp[j] = f2bf(W[k * D + n]);
    }
}

// h (f32) -> hbf (bf16)
__global__ void h2bf(const float* __restrict__ h, short* __restrict__ hbf) {
    int t = blockIdx.x * blockDim.x + threadIdx.x;
    if (t >= N_NODES * D / 8) return;
    f32x4 a = ((const f32x4*)h)[2 * t];
    f32x4 b = ((const f32x4*)h)[2 * t + 1];
    bf16x8 o;
    o[0] = f2bf(a.x); o[1] = f2bf(a.y); o[2] = f2bf(a.z); o[3] = f2bf(a.w);
    o[4] = f2bf(b.x); o[5] = f2bf(b.y); o[6] = f2bf(b.z); o[7] = f2bf(b.w);
    ((bf16x8*)hbf)[t] = o;
}

// fill padded edge segments with sentinel (src=0, dst-byte=0x80) + zero gcnt
__global__ void pad_init(int* __restrict__ esd, int* __restrict__ gcnt) {
    int i = blockIdx.x * blockDim.x + threadIdx.x;
    if (i < NGROUP * GSTRIDE) esd[i] = 0x80;
    if (i < NGROUP) gcnt[i] = 0;
}

// ---------------------------------------------------------------------------
// Edge binning into fixed-stride per-group segments.
// esd[slot] = (src << 8) | (dst & 15); one packed store per edge.
// ---------------------------------------------------------------------------
__global__ __launch_bounds__(256) void scatter(const int* __restrict__ src,
                                               const int* __restrict__ dst,
                                               int* __restrict__ gcnt,
                                               int* __restrict__ esd) {
    __shared__ int hcnt[NGROUP];
    __shared__ int hbase[NGROUP];
    for (int i = threadIdx.x; i < NGROUP; i += 256) hcnt[i] = 0;
    __syncthreads();
    int base = blockIdx.x * EPB;
    int end = base + EPB; if (end > N_EDGES) end = N_EDGES;
    for (int e = base + threadIdx.x; e < end; e += 256)
        atomicAdd(&hcnt[dst[e] >> 4], 1);
    __syncthreads();
    for (int i = threadIdx.x; i < NGROUP; i += 256) {
        int c = hcnt[i];
        hbase[i] = c ? atomicAdd(&gcnt[i], c) : 0;
        hcnt[i] = 0;                          // reuse as local rank cursor
    }
    __syncthreads();
    for (int e = base + threadIdx.x; e < end; e += 256) {
        int s = src[e], d = dst[e];
        int g = d >> 4;
        int r = atomicAdd(&hcnt[g], 1);
        int slot = hbase[g] + r;
        if (slot < CAPG)
            esd[(size_t)g * GSTRIDE + slot] = (s << 8) | (d & 15);
    }
}

// ---------------------------------------------------------------------------
// Fused GIN layer. Block = 16 nodes (grid exactly NGROUP), 4 waves.
// Depth-2 staging pipeline: 3 LDS buffers, all chunk indices preloaded to
// VGPRs, 2 VMEM ops/iter, counted vmcnt(4) => each stage has ~2 iterations
// in flight. Mask bytes come from a 384B LDS table built in the prologue.
// Self term (1+eps)*h folded into the accumulator epilogue (no MFMA chunk).
// ---------------------------------------------------------------------------
__global__ __launch_bounds__(256) void gin_layer(const short* __restrict__ hbf,
                                                 const int* __restrict__ gcnt,
                                                 const int* __restrict__ esd,
                                                 const short* __restrict__ Wl,
                                                 const float* __restrict__ b1,
                                                 const float* __restrict__ b2,
                                                 const float* __restrict__ eps, int l,
                                                 float* __restrict__ outf,
                                                 short* __restrict__ outbf, int last) {
    __shared__ union {
        short stg[3][4096];                           // 3 x 8KB staging
        struct { short zl[2048]; short hl[2048]; } t; // MLP tiles (overlay)
    } sm;
    __shared__ unsigned char dmask[512];              // per-slot dst bytes

    const int lane = threadIdx.x & 63;
    const int wid  = threadIdx.x >> 6;
    const int g    = blockIdx.x;
    const int n0   = g * 16;
    const int m    = lane & 15;          // A-row (node) / C-col
    const int kh   = lane >> 4;          // k-quarter

    // staging lane -> (edge slot, col half)
    const int s_    = lane >> 3;
    const int kr_   = 2 * (s_ & 3) + (s_ >> 2);
    const int eL    = kr_ * 4 + ((lane & 7) >> 1);   // edge slot 0..31
    const int chalf = lane & 1;
    const int kcA   = wid * 2, kcB = wid * 2 + 1;

    const char* hby = (const char*)hbf;
    const int lo  = g * GSTRIDE;
    int cnt = gcnt[g]; if (cnt > CAPG) cnt = CAPG;
    const int nch = (cnt + 31) >> 5;                 // 0..12
    const uint32_t one = 0x3F80u;

    const uint32_t stg_base =
        (uint32_t)(uintptr_t)(__attribute__((address_space(3))) short*)&sm.stg[0][0];

    f32x4 acc[2];
    acc[0] = (f32x4)(0.0f); acc[1] = (f32x4)(0.0f);

#define STAGE(b, gp) do { \
        const char* _g = (gp); \
        __builtin_amdgcn_global_load_lds( \
            (const __attribute__((address_space(1))) void*)(_g + kcA * 32), \
            (__attribute__((address_space(3))) void*)(&sm.stg[(b)][0] + kcA * 512), 16, 0, 0); \
        __builtin_amdgcn_global_load_lds( \
            (const __attribute__((address_space(1))) void*)(_g + kcB * 32), \
            (__attribute__((address_space(3))) void*)(&sm.stg[(b)][0] + kcB * 512), 16, 0, 0); \
    } while (0)

    auto mfma_tiles = [&](int b, bf16x8 am) {
#pragma unroll
        for (int t = 0; t < 2; ++t) {
            uint32_t a0 = stg_base + (uint32_t)(b * 8192 + (wid * 2 + t) * 1024 + lane * 8);
            uint64_t r0, r1;
            asm volatile("ds_read_b64_tr_b16 %0, %1" : "=v"(r0) : "v"(a0));
            asm volatile("ds_read_b64_tr_b16 %0, %1 offset:512" : "=v"(r1) : "v"(a0));
            asm volatile("s_waitcnt lgkmcnt(0)" ::: "memory");
            __builtin_amdgcn_sched_barrier(0);
            union { uint64_t u[2]; bf16x8 v; } bb;
            bb.u[0] = r0; bb.u[1] = r1;
            acc[t] = __builtin_amdgcn_mfma_f32_16x16x32_bf16(am, bb.v, acc[t], 0, 0, 0);
        }
    };

    const int* ep = esd + lo;

    // ---- prologue: preload ALL chunk indices (slot eL of each chunk) ----
    int esv[MAXCH];
#pragma unroll
    for (int c = 0; c < MAXCH; ++c) esv[c] = ep[c * 32 + eL];

    // stage chunks 0 and 1 (depth-2 head)
    STAGE(0, hby + (uint32_t)(esv[0] & ~0xFF) + chalf * 16);
    STAGE(1, hby + (uint32_t)(esv[1] & ~0xFF) + chalf * 16);

    // build the dst-byte table (all waves write identical values)
#pragma unroll
    for (int c = 0; c < MAXCH; ++c)
        dmask[c * 32 + eL] = (unsigned char)(esv[c] & 0xFF);
    asm volatile("s_waitcnt lgkmcnt(0)" ::: "memory");
    __builtin_amdgcn_s_barrier();     // raw barrier: does NOT drain vmcnt

    // ---- chunk loop: 2 VMEM/iter, vmcnt(4) => stage c has ~2 iters in flight
#pragma unroll
    for (int c = 0; c < MAXCH; ++c) {
        if (c >= nch) break;
        if (c + 2 < nch) {
            STAGE((c + 2) % 3, hby + (uint32_t)(esv[c + 2] & ~0xFF) + chalf * 16);
            asm volatile("s_waitcnt vmcnt(4)" ::: "memory");
        } else if (c + 1 < nch) {
            asm volatile("s_waitcnt vmcnt(2)" ::: "memory");
        } else {
            asm volatile("s_waitcnt vmcnt(0)" ::: "memory");
        }
        __builtin_amdgcn_sched_barrier(0);
        uint2 dm = *(const uint2*)&dmask[c * 32 + kh * 8];
        bf16x8 am;
#pragma unroll
        for (int e = 0; e < 4; ++e) {
            am[e]     = (((dm.x >> (e * 8)) & 255u) == (uint32_t)m) ? (short)one : (short)0;
            am[e + 4] = (((dm.y >> (e * 8)) & 255u) == (uint32_t)m) ? (short)one : (short)0;
        }
        mfma_tiles(c % 3, am);
    }

    // ---- self term: acc += (1+eps) * h[self] at this lane's C positions ----
    {
        const float se = 1.0f + eps[l];
#pragma unroll
        for (int t = 0; t < 2; ++t) {
            int col = (wid * 2 + t) * 16 + m;
#pragma unroll
            for (int r = 0; r < 4; ++r) {
                int row = n0 + kh * 4 + r;
                acc[t][r] += se * bf2f(hbf[(size_t)row * D + col]);
            }
        }
    }

    __syncthreads();   // all waves done with stg; safe to overlay zl/hl

    // ---- z (C layout) -> zl LDS, granule-swizzled for MLP A-frags ----
#pragma unroll
    for (int t = 0; t < 2; ++t) {
        int col = (wid * 2 + t) * 16 + m;
        int gi = col >> 3, ci = col & 7;
#pragma unroll
        for (int r = 0; r < 4; ++r) {
            int row = kh * 4 + r;
            sm.t.zl[row * 128 + ((gi ^ (row & 7)) << 3) + ci] = f2bf(acc[t][r]);
        }
    }
    __syncthreads();

    // ---- MLP stage 1: hid = relu(z @ W1 + b1) ----
    f32x4 acc1[2];
    acc1[0] = (f32x4)(0.0f); acc1[1] = (f32x4)(0.0f);
#pragma unroll
    for (int ks = 0; ks < 4; ++ks) {
        int gidx = ks * 4 + kh;
        bf16x8 af = *(const bf16x8*)&sm.t.zl[m * 128 + ((gidx ^ (m & 7)) * 8)];
#pragma unroll
        for (int t = 0; t < 2; ++t) {
            int nt = wid * 2 + t;
            bf16x8 bf = *(const bf16x8*)(Wl + ((size_t)(ks * 8 + nt) * 64 + lane) * 8);
            acc1[t] = __builtin_amdgcn_mfma_f32_16x16x32_bf16(af, bf, acc1[t], 0, 0, 0);
        }
    }
#pragma unroll
    for (int t = 0; t < 2; ++t) {
        int col = (wid * 2 + t) * 16 + m;
        float bias = b1[col];
#pragma unroll
        for (int r = 0; r < 4; ++r) {
            int hrow = kh * 4 + r;
            float v = fmaxf(acc1[t][r] + bias, 0.0f);
            sm.t.hl[hrow * 128 + (col ^ ((hrow & 7) << 3))] = f2bf(v);
        }
    }
    __syncthreads();

    // ---- MLP stage 2: out = hid @ W2 + b2 ----
    f32x4 acc2[2];
    acc2[0] = (f32x4)(0.0f); acc2[1] = (f32x4)(0.0f);
    const short* W2p = Wl + 4 * 8 * 64 * 8;
#pragma unroll
    for (int ks = 0; ks < 4; ++ks) {
        int c0 = ks * 32 + kh * 8;
        bf16x8 af = *(const bf16x8*)&sm.t.hl[m * 128 + (c0 ^ ((m & 7) << 3))];
#pragma unroll
        for (int t = 0; t < 2; ++t) {
            int nt = wid * 2 + t;
            bf16x8 bf = *(const bf16x8*)(W2p + ((size_t)(ks * 8 + nt) * 64 + lane) * 8);
            acc2[t] = __builtin_amdgcn_mfma_f32_16x16x32_bf16(af, bf, acc2[t], 0, 0, 0);
        }
    }
#pragma unroll
    for (int t = 0; t < 2; ++t) {
        int col = (wid * 2 + t) * 16 + m;
        float bias = b2[col];
#pragma unroll
        for (int r = 0; r < 4; ++r) {
            int orow = n0 + kh * 4 + r;        // exact grid, always < N_NODES
            float v = acc2[t][r] + bias;
            if (last) outf[(size_t)orow * D + col] = v;
            else      outbf[(size_t)orow * D + col] = f2bf(v);
        }
    }
#undef STAGE
}

extern "C" void kernel_launch(void* const* d_in, const int* in_sizes, int n_in,
                              void* d_out, int out_size, void* d_ws, size_t ws_size,
                              hipStream_t stream) {
    const float* h   = (const float*)d_in[0];
    const int*   src = (const int*)d_in[1];
    const int*   dst = (const int*)d_in[2];
    const float* W1  = (const float*)d_in[3];
    const float* b1  = (const float*)d_in[4];
    const float* W2  = (const float*)d_in[5];
    const float* b2  = (const float*)d_in[6];
    const float* eps = (const float*)d_in[7];
    float* out = (float*)d_out;

    char* ws = (char*)d_ws;
    const size_t MB = 1024 * 1024;
    short* hbfA = (short*)ws;                          // 12.8 MB
    short* hbfB = (short*)(ws + 13 * MB);              // 12.8 MB
    short* Wswz = (short*)(ws + 26 * MB);              // 196 KB
    int*   gcnt = (int*)(ws + 27 * MB);                // 12.5 KB
    int*   esd  = (int*)(ws + 28 * MB);                // 6.4 MB

    wconv<<<48, 256, 0, stream>>>(W1, W2, Wswz);
    h2bf<<<(N_NODES * D / 8 + 255) / 256, 256, 0, stream>>>(h, hbfA);
    pad_init<<<(NGROUP * GSTRIDE + 255) / 256, 256, 0, stream>>>(esd, gcnt);
    scatter<<<SC_BLOCKS, 256, 0, stream>>>(src, dst, gcnt, esd);

    const short* hin[3]   = {hbfA, hbfB, hbfA};
    short*      houtbf[3] = {hbfB, hbfA, nullptr};

    for (int l = 0; l < NLAYER; ++l) {
        gin_layer<<<NGROUP, 256, 0, stream>>>(hin[l], gcnt, esd,
                                              Wswz + (size_t)l * 2 * 16384,
                                              b1 + (size_t)l * D, b2 + (size_t)l * D,
                                              eps, l, out, houtbf[l],
                                              l == NLAYER - 1 ? 1 : 0);
    }
}

// Round 9
// 150.593 us; speedup vs baseline: 1.1827x; 1.1827x over previous
//
#include <hip/hip_runtime.h>
#include <hip/hip_bf16.h>
#include <stdint.h>

#define N_NODES 50000
#define N_EDGES 800000
#define D 128
#define NLAYER 3
#define NGROUP (N_NODES / 16)     // 3125 groups of 16 nodes
#define CAPG 384                   // max edges per group (Poisson(256) + 8 sigma)
#define GSTRIDE 384                // segment stride == CAPG (prologue reads < 384)
#define MAXCH 12                   // CAPG/32

#define NBKT2 196                  // coarse buckets of 256 nodes (dst >> 8)
#define BCAP 4608                  // bucket capacity (Poisson(4082) + ~8 sigma)
#define EPB_A 2048
#define PA_BLOCKS ((N_EDGES + EPB_A - 1) / EPB_A)   // 391

typedef __attribute__((ext_vector_type(8))) short bf16x8;
typedef __attribute__((ext_vector_type(4))) float f32x4;

__device__ __forceinline__ short f2bf(float f) {
    union { float f; uint32_t u; } v; v.f = f;
    uint32_t u = v.u;
    uint32_t r = u + 0x7fffu + ((u >> 16) & 1u);   // round-to-nearest-even
    return (short)(r >> 16);
}
__device__ __forceinline__ float bf2f(short s) {
    union { uint32_t u; float f; } v;
    v.u = ((uint32_t)(uint16_t)s) << 16;
    return v.f;
}

// ---------------------------------------------------------------------------
// Weight conversion: bf16, B-fragment-swizzled (one 16B load per lane-frag).
// ---------------------------------------------------------------------------
__global__ void wconv(const float* __restrict__ W1, const float* __restrict__ W2,
                      short* __restrict__ Wswz) {
    int t = blockIdx.x * blockDim.x + threadIdx.x;   // (l,mat,ks,nt,lane)
    if (t >= NLAYER * 2 * 4 * 8 * 64) return;
    int lane = t & 63;
    int nt   = (t >> 6) & 7;
    int ks   = (t >> 9) & 3;
    int mat  = (t >> 11) & 1;
    int l    = t >> 12;
    const float* W = (mat == 0 ? W1 : W2) + (size_t)l * D * D;
    int n = nt * 16 + (lane & 15);
    short* outp = Wswz + (size_t)t * 8;
#pragma unroll
    for (int j = 0; j < 8; ++j) {
        int k = ks * 32 + (lane >> 4) * 8 + j;
        outp[j] = f2bf(W[k * D + n]);
    }
}

// h (f32) -> hbf (bf16)
__global__ void h2bf(const float* __restrict__ h, short* __restrict__ hbf) {
    int t = blockIdx.x * blockDim.x + threadIdx.x;
    if (t >= N_NODES * D / 8) return;
    f32x4 a = ((const f32x4*)h)[2 * t];
    f32x4 b = ((const f32x4*)h)[2 * t + 1];
    bf16x8 o;
    o[0] = f2bf(a.x); o[1] = f2bf(a.y); o[2] = f2bf(a.z); o[3] = f2bf(a.w);
    o[4] = f2bf(b.x); o[5] = f2bf(b.y); o[6] = f2bf(b.z); o[7] = f2bf(b.w);
    ((bf16x8*)hbf)[t] = o;
}

__global__ void zero_bcur(int* __restrict__ bcur) {
    if (threadIdx.x < NBKT2) bcur[threadIdx.x] = 0;
}

// ---------------------------------------------------------------------------
// Pass A: bin edges into 196 fixed-base coarse buckets (256 nodes each).
// epack[slot] = (src << 8) | (dst & 255).  LDS 196-entry two-phase keeps the
// per-(block,bucket) writes in runs of ~10 edges.
// ---------------------------------------------------------------------------
__global__ __launch_bounds__(256) void packA(const int* __restrict__ src,
                                             const int* __restrict__ dst,
                                             int* __restrict__ bcur,
                                             int* __restrict__ epack) {
    __shared__ int hcnt[NBKT2];
    __shared__ int hbase[NBKT2];
    if (threadIdx.x < NBKT2) hcnt[threadIdx.x] = 0;
    __syncthreads();
    int base = blockIdx.x * EPB_A;
    int end = base + EPB_A; if (end > N_EDGES) end = N_EDGES;
    for (int e = base + threadIdx.x; e < end; e += 256)
        atomicAdd(&hcnt[dst[e] >> 8], 1);
    __syncthreads();
    if (threadIdx.x < NBKT2) {
        int c = hcnt[threadIdx.x];
        hbase[threadIdx.x] = c ? atomicAdd(&bcur[threadIdx.x], c) : 0;
        hcnt[threadIdx.x] = 0;               // reuse as local rank cursor
    }
    __syncthreads();
    for (int e = base + threadIdx.x; e < end; e += 256) {
        int s = src[e], d = dst[e];
        int b = d >> 8;
        int r = atomicAdd(&hcnt[b], 1);
        int slot = hbase[b] + r;
        if (slot < BCAP)
            epack[(size_t)b * BCAP + slot] = (s << 8) | (d & 255);
    }
}

// ---------------------------------------------------------------------------
// Pass B: one block per bucket. Rank edges into a per-group LDS segment image
// (16 groups x 384 slots, sentinel 0x80), then stream out fully coalesced.
// esd[slot] = (src << 8) | (dst & 15);  gcnt[g] = exact count (clamped).
// ---------------------------------------------------------------------------
__global__ __launch_bounds__(256) void segB(const int* __restrict__ epack,
                                            const int* __restrict__ bcur,
                                            int* __restrict__ esd,
                                            int* __restrict__ gcnt) {
    __shared__ int image[16 * GSTRIDE];      // 24 KB
    __shared__ int cur[16];
    const int b = blockIdx.x;
    int n = bcur[b]; if (n > BCAP) n = BCAP;
    const int* ep = epack + (size_t)b * BCAP;
    const int nG = (NGROUP - b * 16 < 16) ? (NGROUP - b * 16) : 16;

    for (int i = threadIdx.x; i < 16 * GSTRIDE; i += 256) image[i] = 0x80;
    if (threadIdx.x < 16) cur[threadIdx.x] = 0;
    __syncthreads();
    for (int i = threadIdx.x; i < n; i += 256) {
        int e = ep[i];
        int g = (e >> 4) & 15;
        int r = atomicAdd(&cur[g], 1);
        if (r < CAPG) image[g * GSTRIDE + r] = e & ~0xF0;   // strip group bits
    }
    __syncthreads();
    if (threadIdx.x < nG) {
        int c = cur[threadIdx.x];
        gcnt[b * 16 + threadIdx.x] = (c > CAPG) ? CAPG : c;
    }
    for (int i = threadIdx.x; i < nG * GSTRIDE; i += 256)
        esd[(size_t)(b * 16) * GSTRIDE + i] = image[i];
}

// ---------------------------------------------------------------------------
// Fused GIN layer. Block = 16 nodes (grid exactly NGROUP), 4 waves.
// 2 staging buffers (16.9 KB LDS -> ~9 blocks/CU), preloaded chunk indices,
// LDS dmask table, counted vmcnt(2), self term in the accumulator epilogue.
// ---------------------------------------------------------------------------
__global__ __launch_bounds__(256) void gin_layer(const short* __restrict__ hbf,
                                                 const int* __restrict__ gcnt,
                                                 const int* __restrict__ esd,
                                                 const short* __restrict__ Wl,
                                                 const float* __restrict__ b1,
                                                 const float* __restrict__ b2,
                                                 const float* __restrict__ eps, int l,
                                                 float* __restrict__ outf,
                                                 short* __restrict__ outbf, int last) {
    __shared__ union {
        short stg[2][4096];                           // 2 x 8KB staging
        struct { short zl[2048]; short hl[2048]; } t; // MLP tiles (overlay)
    } sm;
    __shared__ unsigned char dmask[512];              // per-slot dst bytes

    const int lane = threadIdx.x & 63;
    const int wid  = threadIdx.x >> 6;
    const int g    = blockIdx.x;
    const int n0   = g * 16;
    const int m    = lane & 15;          // A-row (node) / C-col
    const int kh   = lane >> 4;          // k-quarter

    // staging lane -> (edge slot, col half)
    const int s_    = lane >> 3;
    const int kr_   = 2 * (s_ & 3) + (s_ >> 2);
    const int eL    = kr_ * 4 + ((lane & 7) >> 1);   // edge slot 0..31
    const int chalf = lane & 1;
    const int kcA   = wid * 2, kcB = wid * 2 + 1;

    const char* hby = (const char*)hbf;
    const int lo  = g * GSTRIDE;
    int cnt = gcnt[g]; if (cnt > CAPG) cnt = CAPG;
    const int nch = (cnt + 31) >> 5;                 // 0..12
    const uint32_t one = 0x3F80u;

    const uint32_t stg_base =
        (uint32_t)(uintptr_t)(__attribute__((address_space(3))) short*)&sm.stg[0][0];

    f32x4 acc[2];
    acc[0] = (f32x4)(0.0f); acc[1] = (f32x4)(0.0f);

#define STAGE(b, gp) do { \
        const char* _g = (gp); \
        __builtin_amdgcn_global_load_lds( \
            (const __attribute__((address_space(1))) void*)(_g + kcA * 32), \
            (__attribute__((address_space(3))) void*)(&sm.stg[(b)][0] + kcA * 512), 16, 0, 0); \
        __builtin_amdgcn_global_load_lds( \
            (const __attribute__((address_space(1))) void*)(_g + kcB * 32), \
            (__attribute__((address_space(3))) void*)(&sm.stg[(b)][0] + kcB * 512), 16, 0, 0); \
    } while (0)

    auto mfma_tiles = [&](int b, bf16x8 am) {
#pragma unroll
        for (int t = 0; t < 2; ++t) {
            uint32_t a0 = stg_base + (uint32_t)(b * 8192 + (wid * 2 + t) * 1024 + lane * 8);
            uint64_t r0, r1;
            asm volatile("ds_read_b64_tr_b16 %0, %1" : "=v"(r0) : "v"(a0));
            asm volatile("ds_read_b64_tr_b16 %0, %1 offset:512" : "=v"(r1) : "v"(a0));
            asm volatile("s_waitcnt lgkmcnt(0)" ::: "memory");
            __builtin_amdgcn_sched_barrier(0);
            union { uint64_t u[2]; bf16x8 v; } bb;
            bb.u[0] = r0; bb.u[1] = r1;
            acc[t] = __builtin_amdgcn_mfma_f32_16x16x32_bf16(am, bb.v, acc[t], 0, 0, 0);
        }
    };

    const int* ep = esd + lo;

    // ---- prologue: preload ALL chunk indices (slot eL of each chunk) ----
    int esv[MAXCH];
#pragma unroll
    for (int c = 0; c < MAXCH; ++c) esv[c] = ep[c * 32 + eL];

    // stage chunk 0
    STAGE(0, hby + (uint32_t)(esv[0] & ~0xFF) + chalf * 16);

    // build the dst-byte table (all waves write identical values)
#pragma unroll
    for (int c = 0; c < MAXCH; ++c)
        dmask[c * 32 + eL] = (unsigned char)(esv[c] & 0xFF);
    asm volatile("s_waitcnt lgkmcnt(0)" ::: "memory");
    __builtin_amdgcn_s_barrier();     // raw barrier: does NOT drain vmcnt

    // ---- chunk loop: 2 VMEM/iter, vmcnt(2) => chunk c ready, c+1 in flight
#pragma unroll
    for (int c = 0; c < MAXCH; ++c) {
        if (c >= nch) break;
        if (c + 1 < nch) {
            STAGE((c + 1) & 1, hby + (uint32_t)(esv[c + 1] & ~0xFF) + chalf * 16);
            asm volatile("s_waitcnt vmcnt(2)" ::: "memory");
        } else {
            asm volatile("s_waitcnt vmcnt(0)" ::: "memory");
        }
        __builtin_amdgcn_sched_barrier(0);
        uint2 dm = *(const uint2*)&dmask[c * 32 + kh * 8];
        bf16x8 am;
#pragma unroll
        for (int e = 0; e < 4; ++e) {
            am[e]     = (((dm.x >> (e * 8)) & 255u) == (uint32_t)m) ? (short)one : (short)0;
            am[e + 4] = (((dm.y >> (e * 8)) & 255u) == (uint32_t)m) ? (short)one : (short)0;
        }
        mfma_tiles(c & 1, am);
    }

    // ---- self term: acc += (1+eps) * h[self] at this lane's C positions ----
    {
        const float se = 1.0f + eps[l];
#pragma unroll
        for (int t = 0; t < 2; ++t) {
            int col = (wid * 2 + t) * 16 + m;
#pragma unroll
            for (int r = 0; r < 4; ++r) {
                int row = n0 + kh * 4 + r;
                acc[t][r] += se * bf2f(hbf[(size_t)row * D + col]);
            }
        }
    }

    __syncthreads();   // drains vmcnt too; safe to overlay zl/hl on stg

    // ---- z (C layout) -> zl LDS, granule-swizzled for MLP A-frags ----
#pragma unroll
    for (int t = 0; t < 2; ++t) {
        int col = (wid * 2 + t) * 16 + m;
        int gi = col >> 3, ci = col & 7;
#pragma unroll
        for (int r = 0; r < 4; ++r) {
            int row = kh * 4 + r;
            sm.t.zl[row * 128 + ((gi ^ (row & 7)) << 3) + ci] = f2bf(acc[t][r]);
        }
    }
    __syncthreads();

    // ---- MLP stage 1: hid = relu(z @ W1 + b1) ----
    f32x4 acc1[2];
    acc1[0] = (f32x4)(0.0f); acc1[1] = (f32x4)(0.0f);
#pragma unroll
    for (int ks = 0; ks < 4; ++ks) {
        int gidx = ks * 4 + kh;
        bf16x8 af = *(const bf16x8*)&sm.t.zl[m * 128 + ((gidx ^ (m & 7)) * 8)];
#pragma unroll
        for (int t = 0; t < 2; ++t) {
            int nt = wid * 2 + t;
            bf16x8 bf = *(const bf16x8*)(Wl + ((size_t)(ks * 8 + nt) * 64 + lane) * 8);
            acc1[t] = __builtin_amdgcn_mfma_f32_16x16x32_bf16(af, bf, acc1[t], 0, 0, 0);
        }
    }
#pragma unroll
    for (int t = 0; t < 2; ++t) {
        int col = (wid * 2 + t) * 16 + m;
        float bias = b1[col];
#pragma unroll
        for (int r = 0; r < 4; ++r) {
            int hrow = kh * 4 + r;
            float v = fmaxf(acc1[t][r] + bias, 0.0f);
            sm.t.hl[hrow * 128 + (col ^ ((hrow & 7) << 3))] = f2bf(v);
        }
    }
    __syncthreads();

    // ---- MLP stage 2: out = hid @ W2 + b2 ----
    f32x4 acc2[2];
    acc2[0] = (f32x4)(0.0f); acc2[1] = (f32x4)(0.0f);
    const short* W2p = Wl + 4 * 8 * 64 * 8;
#pragma unroll
    for (int ks = 0; ks < 4; ++ks) {
        int c0 = ks * 32 + kh * 8;
        bf16x8 af = *(const bf16x8*)&sm.t.hl[m * 128 + (c0 ^ ((m & 7) << 3))];
#pragma unroll
        for (int t = 0; t < 2; ++t) {
            int nt = wid * 2 + t;
            bf16x8 bf = *(const bf16x8*)(W2p + ((size_t)(ks * 8 + nt) * 64 + lane) * 8);
            acc2[t] = __builtin_amdgcn_mfma_f32_16x16x32_bf16(af, bf, acc2[t], 0, 0, 0);
        }
    }
#pragma unroll
    for (int t = 0; t < 2; ++t) {
        int col = (wid * 2 + t) * 16 + m;
        float bias = b2[col];
#pragma unroll
        for (int r = 0; r < 4; ++r) {
            int orow = n0 + kh * 4 + r;        // exact grid, always < N_NODES
            float v = acc2[t][r] + bias;
            if (last) outf[(size_t)orow * D + col] = v;
            else      outbf[(size_t)orow * D + col] = f2bf(v);
        }
    }
#undef STAGE
}

extern "C" void kernel_launch(void* const* d_in, const int* in_sizes, int n_in,
                              void* d_out, int out_size, void* d_ws, size_t ws_size,
                              hipStream_t stream) {
    const float* h   = (const float*)d_in[0];
    const int*   src = (const int*)d_in[1];
    const int*   dst = (const int*)d_in[2];
    const float* W1  = (const float*)d_in[3];
    const float* b1  = (const float*)d_in[4];
    const float* W2  = (const float*)d_in[5];
    const float* b2  = (const float*)d_in[6];
    const float* eps = (const float*)d_in[7];
    float* out = (float*)d_out;

    char* ws = (char*)d_ws;
    const size_t MB = 1024 * 1024;
    short* hbfA = (short*)ws;                          // 12.8 MB
    short* hbfB = (short*)(ws + 13 * MB);              // 12.8 MB
    short* Wswz = (short*)(ws + 26 * MB);              // 196 KB
    int*   gcnt = (int*)(ws + 27 * MB);                // 12.5 KB
    int*   bcur = (int*)(ws + 27 * MB + 512 * 1024);   // 0.8 KB
    int*   esd  = (int*)(ws + 28 * MB);                // 4.8 MB (3125*384*4)
    int*   epack= (int*)(ws + 33 * MB);                // 3.6 MB (196*4608*4)

    wconv<<<48, 256, 0, stream>>>(W1, W2, Wswz);
    h2bf<<<(N_NODES * D / 8 + 255) / 256, 256, 0, stream>>>(h, hbfA);
    zero_bcur<<<1, 256, 0, stream>>>(bcur);
    packA<<<PA_BLOCKS, 256, 0, stream>>>(src, dst, bcur, epack);
    segB<<<NBKT2, 256, 0, stream>>>(epack, bcur, esd, gcnt);

    const short* hin[3]   = {hbfA, hbfB, hbfA};
    short*      houtbf[3] = {hbfB, hbfA, nullptr};

    for (int l = 0; l < NLAYER; ++l) {
        gin_layer<<<NGROUP, 256, 0, stream>>>(hin[l], gcnt, esd,
                                              Wswz + (size_t)l * 2 * 16384,
                                              b1 + (size_t)l * D, b2 + (size_t)l * D,
                                              eps, l, out, houtbf[l],
                                              l == NLAYER - 1 ? 1 : 0);
    }
}

// Round 10
// 141.284 us; speedup vs baseline: 1.2606x; 1.0659x over previous
//
#include <hip/hip_runtime.h>
#include <hip/hip_bf16.h>
#include <stdint.h>

#define N_NODES 50000
#define N_EDGES 800000
#define D 128
#define NLAYER 3
#define NGROUP (N_NODES / 16)     // 3125 groups of 16 nodes
#define CAPG 384                   // max edges per group (Poisson(256) + 8 sigma)
#define GSTRIDE 384                // segment stride == CAPG
#define MAXCH 12                   // CAPG/32

#define NBKT2 196                  // coarse buckets of 256 nodes (dst >> 8)
#define BCAP 4608                  // bucket capacity (Poisson(4082) + ~8 sigma)
#define EPB_A 2048
#define PA_BLOCKS ((N_EDGES + EPB_A - 1) / EPB_A)   // 391

typedef __attribute__((ext_vector_type(8))) short bf16x8;
typedef __attribute__((ext_vector_type(4))) float f32x4;

__device__ __forceinline__ short f2bf(float f) {
    union { float f; uint32_t u; } v; v.f = f;
    uint32_t u = v.u;
    uint32_t r = u + 0x7fffu + ((u >> 16) & 1u);   // round-to-nearest-even
    return (short)(r >> 16);
}
__device__ __forceinline__ float bf2f(short s) {
    union { uint32_t u; float f; } v;
    v.u = ((uint32_t)(uint16_t)s) << 16;
    return v.f;
}

// ---------------------------------------------------------------------------
// Weight conversion: bf16, B-fragment-swizzled (one 16B load per lane-frag).
// ---------------------------------------------------------------------------
__global__ void wconv(const float* __restrict__ W1, const float* __restrict__ W2,
                      short* __restrict__ Wswz) {
    int t = blockIdx.x * blockDim.x + threadIdx.x;   // (l,mat,ks,nt,lane)
    if (t >= NLAYER * 2 * 4 * 8 * 64) return;
    int lane = t & 63;
    int nt   = (t >> 6) & 7;
    int ks   = (t >> 9) & 3;
    int mat  = (t >> 11) & 1;
    int l    = t >> 12;
    const float* W = (mat == 0 ? W1 : W2) + (size_t)l * D * D;
    int n = nt * 16 + (lane & 15);
    short* outp = Wswz + (size_t)t * 8;
#pragma unroll
    for (int j = 0; j < 8; ++j) {
        int k = ks * 32 + (lane >> 4) * 8 + j;
        outp[j] = f2bf(W[k * D + n]);
    }
}

// h (f32) -> hbf (bf16)
__global__ void h2bf(const float* __restrict__ h, short* __restrict__ hbf) {
    int t = blockIdx.x * blockDim.x + threadIdx.x;
    if (t >= N_NODES * D / 8) return;
    f32x4 a = ((const f32x4*)h)[2 * t];
    f32x4 b = ((const f32x4*)h)[2 * t + 1];
    bf16x8 o;
    o[0] = f2bf(a.x); o[1] = f2bf(a.y); o[2] = f2bf(a.z); o[3] = f2bf(a.w);
    o[4] = f2bf(b.x); o[5] = f2bf(b.y); o[6] = f2bf(b.z); o[7] = f2bf(b.w);
    ((bf16x8*)hbf)[t] = o;
}

__global__ void zero_bcur(int* __restrict__ bcur) {
    if (threadIdx.x < NBKT2) bcur[threadIdx.x] = 0;
}

// ---------------------------------------------------------------------------
// Pass A: bin edges into 196 fixed-base coarse buckets (256 nodes each).
// epack[slot] = (src << 8) | (dst & 255).
// ---------------------------------------------------------------------------
__global__ __launch_bounds__(256) void packA(const int* __restrict__ src,
                                             const int* __restrict__ dst,
                                             int* __restrict__ bcur,
                                             int* __restrict__ epack) {
    __shared__ int hcnt[NBKT2];
    __shared__ int hbase[NBKT2];
    if (threadIdx.x < NBKT2) hcnt[threadIdx.x] = 0;
    __syncthreads();
    int base = blockIdx.x * EPB_A;
    int end = base + EPB_A; if (end > N_EDGES) end = N_EDGES;
    for (int e = base + threadIdx.x; e < end; e += 256)
        atomicAdd(&hcnt[dst[e] >> 8], 1);
    __syncthreads();
    if (threadIdx.x < NBKT2) {
        int c = hcnt[threadIdx.x];
        hbase[threadIdx.x] = c ? atomicAdd(&bcur[threadIdx.x], c) : 0;
        hcnt[threadIdx.x] = 0;               // reuse as local rank cursor
    }
    __syncthreads();
    for (int e = base + threadIdx.x; e < end; e += 256) {
        int s = src[e], d = dst[e];
        int b = d >> 8;
        int r = atomicAdd(&hcnt[b], 1);
        int slot = hbase[b] + r;
        if (slot < BCAP)
            epack[(size_t)b * BCAP + slot] = (s << 8) | (d & 255);
    }
}

// ---------------------------------------------------------------------------
// Pass B: one block per bucket -> per-group fixed segments, coalesced out.
// esd[slot] = (src << 8) | (dst & 15);  gcnt[g] = exact count (clamped).
// ---------------------------------------------------------------------------
__global__ __launch_bounds__(256) void segB(const int* __restrict__ epack,
                                            const int* __restrict__ bcur,
                                            int* __restrict__ esd,
                                            int* __restrict__ gcnt) {
    __shared__ int image[16 * GSTRIDE];      // 24 KB
    __shared__ int cur[16];
    const int b = blockIdx.x;
    int n = bcur[b]; if (n > BCAP) n = BCAP;
    const int* ep = epack + (size_t)b * BCAP;
    const int nG = (NGROUP - b * 16 < 16) ? (NGROUP - b * 16) : 16;

    for (int i = threadIdx.x; i < 16 * GSTRIDE; i += 256) image[i] = 0x80;
    if (threadIdx.x < 16) cur[threadIdx.x] = 0;
    __syncthreads();
    for (int i = threadIdx.x; i < n; i += 256) {
        int e = ep[i];
        int g = (e >> 4) & 15;
        int r = atomicAdd(&cur[g], 1);
        if (r < CAPG) image[g * GSTRIDE + r] = e & ~0xF0;   // strip group bits
    }
    __syncthreads();
    if (threadIdx.x < nG) {
        int c = cur[threadIdx.x];
        gcnt[b * 16 + threadIdx.x] = (c > CAPG) ? CAPG : c;
    }
    for (int i = threadIdx.x; i < nG * GSTRIDE; i += 256)
        esd[(size_t)(b * 16) * GSTRIDE + i] = image[i];
}

// ---------------------------------------------------------------------------
// Fused GIN layer. Block = 16 nodes, 4 waves, depth-2 pipeline (3 buffers).
// Row-major wave staging: instr I covers 16 edges x 64B (full line, fetched
// once). 4 tr_reads (imm offsets) deliver both tiles' B-frags interleaved by
// col-half; shift/or de-interleave; A-mask k-order permuted to match via the
// permuted dmask table: edge(q,i) = 8*(i>>1) + 2q + (i&1).
// ---------------------------------------------------------------------------
__global__ __launch_bounds__(256) void gin_layer(const short* __restrict__ hbf,
                                                 const int* __restrict__ gcnt,
                                                 const int* __restrict__ esd,
                                                 const short* __restrict__ Wl,
                                                 const float* __restrict__ b1,
                                                 const float* __restrict__ b2,
                                                 const float* __restrict__ eps, int l,
                                                 float* __restrict__ outf,
                                                 short* __restrict__ outbf, int last) {
    __shared__ union {
        short stg[3][4096];                           // 3 x 8KB staging
        struct { short zl[2048]; short hl[2048]; } t; // MLP tiles (overlay)
    } sm;
    __shared__ __align__(8) unsigned char dmask[512]; // permuted dst bytes

    const int lane = threadIdx.x & 63;
    const int wid  = threadIdx.x >> 6;
    const int g    = blockIdx.x;
    const int n0   = g * 16;
    const int m    = lane & 15;          // A-row (node) / C-col
    const int kh   = lane >> 4;          // k-quarter (q)

    const char* hby = (const char*)hbf;
    const int lo  = g * GSTRIDE;
    int cnt = gcnt[g]; if (cnt > CAPG) cnt = CAPG;
    const int nch = (cnt + 31) >> 5;                 // 0..12
    const uint32_t one = 0x3F80u;

    const int sl = lane >> 2;                        // edge sub-slot 0..15
    const int wq = wid * 64 + (lane & 3) * 16;       // byte offset in row

    const uint32_t stg_base =
        (uint32_t)(uintptr_t)(__attribute__((address_space(3))) short*)&sm.stg[0][0];

    f32x4 acc[2];
    acc[0] = (f32x4)(0.0f); acc[1] = (f32x4)(0.0f);

#define STAGE(b, rA, rB) do { \
        __builtin_amdgcn_global_load_lds( \
            (const __attribute__((address_space(1))) void*)(hby + (uint32_t)((rA) & ~0xFF) + wq), \
            (__attribute__((address_space(3))) void*)(&sm.stg[(b)][0] + wid * 1024), 16, 0, 0); \
        __builtin_amdgcn_global_load_lds( \
            (const __attribute__((address_space(1))) void*)(hby + (uint32_t)((rB) & ~0xFF) + wq), \
            (__attribute__((address_space(3))) void*)(&sm.stg[(b)][0] + wid * 1024 + 512), 16, 0, 0); \
    } while (0)

    const int* ep = esd + lo;

    // ---- prologue: preload per-lane edge words for all chunks ----
    int esvA[MAXCH], esvB[MAXCH];
#pragma unroll
    for (int c = 0; c < MAXCH; ++c) {
        esvA[c] = ep[c * 32 + sl];
        esvB[c] = ep[c * 32 + 16 + sl];
    }

    STAGE(0, esvA[0], esvB[0]);
    STAGE(1, esvA[1], esvB[1]);

    // permuted dmask table: pos(s) = q(s)*8 + i(s), q=(s>>1)&3, i=2*(s>>3)+(s&1)
    if (wid == 0 && (lane & 3) == 0) {
        const int sA = sl, sB = 16 + sl;
        const int pA = ((sA >> 1) & 3) * 8 + 2 * (sA >> 3) + (sA & 1);
        const int pB = ((sB >> 1) & 3) * 8 + 2 * (sB >> 3) + (sB & 1);
#pragma unroll
        for (int c = 0; c < MAXCH; ++c) {
            dmask[c * 32 + pA] = (unsigned char)(esvA[c] & 0xFF);
            dmask[c * 32 + pB] = (unsigned char)(esvB[c] & 0xFF);
        }
    }
    asm volatile("s_waitcnt lgkmcnt(0)" ::: "memory");
    __builtin_amdgcn_s_barrier();     // raw barrier: does NOT drain vmcnt

    // ---- chunk loop: depth-2 (stage c+2 while computing c), vmcnt(4) ----
#pragma unroll
    for (int c = 0; c < MAXCH; ++c) {
        if (c >= nch) break;
        if (c + 2 < nch) {
            STAGE((c + 2) % 3, esvA[c + 2], esvB[c + 2]);
            asm volatile("s_waitcnt vmcnt(4)" ::: "memory");
        } else if (c + 1 < nch) {
            asm volatile("s_waitcnt vmcnt(2)" ::: "memory");
        } else {
            asm volatile("s_waitcnt vmcnt(0)" ::: "memory");
        }
        __builtin_amdgcn_sched_barrier(0);

        // 4 tr reads (both tiles interleaved) + dmask read, one lgkm wait
        uint32_t breg = stg_base + (uint32_t)((c % 3) * 8192 + wid * 2048) + lane * 8;
        uint64_t t0, t1, t2, t3;
        asm volatile("ds_read_b64_tr_b16 %0, %1"             : "=v"(t0) : "v"(breg));
        asm volatile("ds_read_b64_tr_b16 %0, %1 offset:512"  : "=v"(t1) : "v"(breg));
        asm volatile("ds_read_b64_tr_b16 %0, %1 offset:1024" : "=v"(t2) : "v"(breg));
        asm volatile("ds_read_b64_tr_b16 %0, %1 offset:1536" : "=v"(t3) : "v"(breg));
        uint2 dm = *(const uint2*)&dmask[c * 32 + kh * 8];
        asm volatile("s_waitcnt lgkmcnt(0)" ::: "memory");
        __builtin_amdgcn_sched_barrier(0);

        // de-interleave col-halves -> tile0/tile1 fragments
        union U64 { uint64_t u; uint32_t d[2]; };
        U64 p0, p1, p2, p3; p0.u = t0; p1.u = t1; p2.u = t2; p3.u = t3;
        union { uint32_t w[4]; bf16x8 v; } bf0, bf1;
        bf0.w[0] = (p0.d[0] & 0xFFFFu) | (p0.d[1] << 16);
        bf1.w[0] = (p0.d[0] >> 16) | (p0.d[1] & 0xFFFF0000u);
        bf0.w[1] = (p1.d[0] & 0xFFFFu) | (p1.d[1] << 16);
        bf1.w[1] = (p1.d[0] >> 16) | (p1.d[1] & 0xFFFF0000u);
        bf0.w[2] = (p2.d[0] & 0xFFFFu) | (p2.d[1] << 16);
        bf1.w[2] = (p2.d[0] >> 16) | (p2.d[1] & 0xFFFF0000u);
        bf0.w[3] = (p3.d[0] & 0xFFFFu) | (p3.d[1] << 16);
        bf1.w[3] = (p3.d[0] >> 16) | (p3.d[1] & 0xFFFF0000u);

        bf16x8 am;
#pragma unroll
        for (int e = 0; e < 4; ++e) {
            am[e]     = (((dm.x >> (e * 8)) & 255u) == (uint32_t)m) ? (short)one : (short)0;
            am[e + 4] = (((dm.y >> (e * 8)) & 255u) == (uint32_t)m) ? (short)one : (short)0;
        }
        acc[0] = __builtin_amdgcn_mfma_f32_16x16x32_bf16(am, bf0.v, acc[0], 0, 0, 0);
        acc[1] = __builtin_amdgcn_mfma_f32_16x16x32_bf16(am, bf1.v, acc[1], 0, 0, 0);
    }

    // ---- self term: acc += (1+eps) * h[self] at this lane's C positions ----
    {
        const float se = 1.0f + eps[l];
#pragma unroll
        for (int t = 0; t < 2; ++t) {
            int col = (wid * 2 + t) * 16 + m;
#pragma unroll
            for (int r = 0; r < 4; ++r) {
                int row = n0 + kh * 4 + r;
                acc[t][r] += se * bf2f(hbf[(size_t)row * D + col]);
            }
        }
    }

    __syncthreads();   // drains vmcnt; safe to overlay zl/hl on stg

    // ---- z (C layout) -> zl LDS, granule-swizzled for MLP A-frags ----
#pragma unroll
    for (int t = 0; t < 2; ++t) {
        int col = (wid * 2 + t) * 16 + m;
        int gi = col >> 3, ci = col & 7;
#pragma unroll
        for (int r = 0; r < 4; ++r) {
            int row = kh * 4 + r;
            sm.t.zl[row * 128 + ((gi ^ (row & 7)) << 3) + ci] = f2bf(acc[t][r]);
        }
    }
    __syncthreads();

    // ---- MLP stage 1: hid = relu(z @ W1 + b1) ----
    f32x4 acc1[2];
    acc1[0] = (f32x4)(0.0f); acc1[1] = (f32x4)(0.0f);
#pragma unroll
    for (int ks = 0; ks < 4; ++ks) {
        int gidx = ks * 4 + kh;
        bf16x8 af = *(const bf16x8*)&sm.t.zl[m * 128 + ((gidx ^ (m & 7)) * 8)];
#pragma unroll
        for (int t = 0; t < 2; ++t) {
            int nt = wid * 2 + t;
            bf16x8 bf = *(const bf16x8*)(Wl + ((size_t)(ks * 8 + nt) * 64 + lane) * 8);
            acc1[t] = __builtin_amdgcn_mfma_f32_16x16x32_bf16(af, bf, acc1[t], 0, 0, 0);
        }
    }
#pragma unroll
    for (int t = 0; t < 2; ++t) {
        int col = (wid * 2 + t) * 16 + m;
        float bias = b1[col];
#pragma unroll
        for (int r = 0; r < 4; ++r) {
            int hrow = kh * 4 + r;
            float v = fmaxf(acc1[t][r] + bias, 0.0f);
            sm.t.hl[hrow * 128 + (col ^ ((hrow & 7) << 3))] = f2bf(v);
        }
    }
    __syncthreads();

    // ---- MLP stage 2: out = hid @ W2 + b2 ----
    f32x4 acc2[2];
    acc2[0] = (f32x4)(0.0f); acc2[1] = (f32x4)(0.0f);
    const short* W2p = Wl + 4 * 8 * 64 * 8;
#pragma unroll
    for (int ks = 0; ks < 4; ++ks) {
        int c0 = ks * 32 + kh * 8;
        bf16x8 af = *(const bf16x8*)&sm.t.hl[m * 128 + (c0 ^ ((m & 7) << 3))];
#pragma unroll
        for (int t = 0; t < 2; ++t) {
            int nt = wid * 2 + t;
            bf16x8 bf = *(const bf16x8*)(W2p + ((size_t)(ks * 8 + nt) * 64 + lane) * 8);
            acc2[t] = __builtin_amdgcn_mfma_f32_16x16x32_bf16(af, bf, acc2[t], 0, 0, 0);
        }
    }
#pragma unroll
    for (int t = 0; t < 2; ++t) {
        int col = (wid * 2 + t) * 16 + m;
        float bias = b2[col];
#pragma unroll
        for (int r = 0; r < 4; ++r) {
            int orow = n0 + kh * 4 + r;        // exact grid, always < N_NODES
            float v = acc2[t][r] + bias;
            if (last) outf[(size_t)orow * D + col] = v;
            else      outbf[(size_t)orow * D + col] = f2bf(v);
        }
    }
#undef STAGE
}

extern "C" void kernel_launch(void* const* d_in, const int* in_sizes, int n_in,
                              void* d_out, int out_size, void* d_ws, size_t ws_size,
                              hipStream_t stream) {
    const float* h   = (const float*)d_in[0];
    const int*   src = (const int*)d_in[1];
    const int*   dst = (const int*)d_in[2];
    const float* W1  = (const float*)d_in[3];
    const float* b1  = (const float*)d_in[4];
    const float* W2  = (const float*)d_in[5];
    const float* b2  = (const float*)d_in[6];
    const float* eps = (const float*)d_in[7];
    float* out = (float*)d_out;

    char* ws = (char*)d_ws;
    const size_t MB = 1024 * 1024;
    short* hbfA = (short*)ws;                          // 12.8 MB
    short* hbfB = (short*)(ws + 13 * MB);              // 12.8 MB
    short* Wswz = (short*)(ws + 26 * MB);              // 196 KB
    int*   gcnt = (int*)(ws + 27 * MB);                // 12.5 KB
    int*   bcur = (int*)(ws + 27 * MB + 512 * 1024);   // 0.8 KB
    int*   esd  = (int*)(ws + 28 * MB);                // 4.8 MB (3125*384*4)
    int*   epack= (int*)(ws + 33 * MB);                // 3.6 MB (196*4608*4)

    wconv<<<48, 256, 0, stream>>>(W1, W2, Wswz);
    h2bf<<<(N_NODES * D / 8 + 255) / 256, 256, 0, stream>>>(h, hbfA);
    zero_bcur<<<1, 256, 0, stream>>>(bcur);
    packA<<<PA_BLOCKS, 256, 0, stream>>>(src, dst, bcur, epack);
    segB<<<NBKT2, 256, 0, stream>>>(epack, bcur, esd, gcnt);

    const short* hin[3]   = {hbfA, hbfB, hbfA};
    short*      houtbf[3] = {hbfB, hbfA, nullptr};

    for (int l = 0; l < NLAYER; ++l) {
        gin_layer<<<NGROUP, 256, 0, stream>>>(hin[l], gcnt, esd,
                                              Wswz + (size_t)l * 2 * 16384,
                                              b1 + (size_t)l * D, b2 + (size_t)l * D,
                                              eps, l, out, houtbf[l],
                                              l == NLAYER - 1 ? 1 : 0);
    }
}